// Round 1
// baseline (20.810 us; speedup 1.0000x reference)
//
#include <hip/hip_runtime.h>
#include <hip/hip_bf16.h>

// SAXSMSAAttention collapses algebraically:
//   kv_x = layer_norm(saxs[...,None]) over a size-1 axis == ln_k_b (exact: x-mu==0)
//   => k[l,:] and v[l,:] constant over l
//   => softmax over l is exactly uniform (1/512, power of two)
//   => o[b,q,:] = v_const, independent of q  (whole Q path cancels)
//   => out = msa + c,  c = (ln_k_b*Wv + bv) @ Wo + bo   (a 256-vector)
// Valid for ANY finite input values, so we compute c on-device from the
// actual input buffers.

#define D 256  // C_HID * N_HEADS == C_Q == 256

// One block, 256 threads: c[j] = sum_i (ln_k_b*Wv[i] + bv[i]) * Wo[i*D + j] + bo[j]
__global__ void saxs_msa_compute_c(const float* __restrict__ ln_k_b,
                                   const float* __restrict__ Wv,
                                   const float* __restrict__ bv,
                                   const float* __restrict__ Wo,
                                   const float* __restrict__ bo,
                                   float* __restrict__ c) {
    __shared__ float v[D];
    const int j = threadIdx.x;
    const float kb = ln_k_b[0];
    v[j] = kb * Wv[j] + bv[j];
    __syncthreads();
    float acc = bo[j];
#pragma unroll 8
    for (int i = 0; i < D; ++i) {
        acc += v[i] * Wo[i * D + j];
    }
    c[j] = acc;
}

// Broadcast-add: out[q*D + j] = msa[q*D + j] + c[j], float4-vectorized.
__global__ void saxs_msa_add_c(const float* __restrict__ msa,
                               const float* __restrict__ c,
                               float* __restrict__ out,
                               int n4) {
    __shared__ float4 cs[D / 4];
    if (threadIdx.x < D / 4) {
        cs[threadIdx.x] = reinterpret_cast<const float4*>(c)[threadIdx.x];
    }
    __syncthreads();
    int idx = blockIdx.x * blockDim.x + threadIdx.x;
    const int stride = gridDim.x * blockDim.x;
    const float4* __restrict__ m4 = reinterpret_cast<const float4*>(msa);
    float4* __restrict__ o4 = reinterpret_cast<float4*>(out);
    for (int i = idx; i < n4; i += stride) {
        float4 m = m4[i];
        float4 cc = cs[i & (D / 4 - 1)];
        m.x += cc.x; m.y += cc.y; m.z += cc.z; m.w += cc.w;
        o4[i] = m;
    }
}

extern "C" void kernel_launch(void* const* d_in, const int* in_sizes, int n_in,
                              void* d_out, int out_size, void* d_ws, size_t ws_size,
                              hipStream_t stream) {
    // setup_inputs order:
    // 0 msa, 1 saxs, 2 ln_q_w, 3 ln_q_b, 4 ln_k_w, 5 ln_k_b,
    // 6 Wq, 7 bq, 8 Wk, 9 bk, 10 Wv, 11 bv, 12 Wo, 13 bo
    const float* msa    = (const float*)d_in[0];
    const float* ln_k_b = (const float*)d_in[5];
    const float* Wv     = (const float*)d_in[10];
    const float* bv     = (const float*)d_in[11];
    const float* Wo     = (const float*)d_in[12];
    const float* bo     = (const float*)d_in[13];
    float* out = (float*)d_out;
    float* c   = (float*)d_ws;  // 256 floats of scratch

    saxs_msa_compute_c<<<1, D, 0, stream>>>(ln_k_b, Wv, bv, Wo, bo, c);

    const int n4 = out_size / 4;  // 4,194,304 / 4 = 1,048,576 float4s
    const int block = 256;
    int grid = (n4 + block - 1) / block;
    if (grid > 2048) grid = 2048;  // grid-stride the rest
    saxs_msa_add_c<<<grid, block, 0, stream>>>(msa, c, out, n4);
}

// Round 2
// 14.873 us; speedup vs baseline: 1.3992x; 1.3992x over previous
//
#include <hip/hip_runtime.h>
#include <hip/hip_bf16.h>

// SAXSMSAAttention collapses algebraically:
//   kv_x = layer_norm(saxs[...,None]) over a size-1 axis == ln_k_b (exact: x-mu==0)
//   => k[l,:], v[l,:] constant over l => softmax exactly uniform (1/512)
//   => o[b,q,:] = v_const (whole Q path cancels)
//   => out = msa + c,  c = (ln_k_b*Wv + bv) @ Wo + bo   (a 256-vector)
// Valid for any finite inputs; c computed on-device from the actual buffers.

#define D 256          // C_HID * N_HEADS == C_Q == 256
#define ASPLIT 8       // i-dimension split for the matvec partials
#define AROWS (D / ASPLIT)  // 32 rows of Wo per partial block

// Kernel A: 8 blocks x 256 threads. Block b computes
//   partial[b][j] = sum_{i in [32b,32b+32)} (kb*Wv[i]+bv[i]) * Wo[i*D + j]
//                 + (b==0 ? bo[j] : 0)
__global__ __launch_bounds__(D) void saxs_msa_partial_c(
        const float* __restrict__ ln_k_b,
        const float* __restrict__ Wv,
        const float* __restrict__ bv,
        const float* __restrict__ Wo,
        const float* __restrict__ bo,
        float* __restrict__ partial) {
    __shared__ float vsh[AROWS];
    const int j = threadIdx.x;
    const int b = blockIdx.x;
    const int i0 = b * AROWS;
    if (j < AROWS) {
        const float kb = ln_k_b[0];
        vsh[j] = kb * Wv[i0 + j] + bv[i0 + j];
    }
    __syncthreads();
    float acc = (b == 0) ? bo[j] : 0.0f;
#pragma unroll 8
    for (int ii = 0; ii < AROWS; ++ii) {
        acc += vsh[ii] * Wo[(i0 + ii) * D + j];
    }
    partial[b * D + j] = acc;
}

// Kernel B: out[q*D + j] = msa[q*D + j] + c[j], float4-vectorized.
// Prologue sums the 8 partials into LDS; each thread then hoists its
// (loop-invariant, since stride % 64 == 0) float4 of c into a register.
__global__ __launch_bounds__(D) void saxs_msa_add_c(
        const float* __restrict__ msa,
        const float* __restrict__ partial,
        float* __restrict__ out,
        int n4) {
    __shared__ float csf[D];
    const int t = threadIdx.x;
    float csum = 0.0f;
#pragma unroll
    for (int k = 0; k < ASPLIT; ++k) {
        csum += partial[k * D + t];
    }
    csf[t] = csum;
    __syncthreads();

    const float4 cc = reinterpret_cast<const float4*>(csf)[t & 63];

    int idx = blockIdx.x * blockDim.x + t;
    const int stride = gridDim.x * blockDim.x;   // multiple of 64 float4s
    const float4* __restrict__ m4 = reinterpret_cast<const float4*>(msa);
    float4* __restrict__ o4 = reinterpret_cast<float4*>(out);
    for (int i = idx; i < n4; i += stride) {
        float4 m = m4[i];
        m.x += cc.x; m.y += cc.y; m.z += cc.z; m.w += cc.w;
        o4[i] = m;
    }
}

extern "C" void kernel_launch(void* const* d_in, const int* in_sizes, int n_in,
                              void* d_out, int out_size, void* d_ws, size_t ws_size,
                              hipStream_t stream) {
    // setup_inputs order:
    // 0 msa, 1 saxs, 2 ln_q_w, 3 ln_q_b, 4 ln_k_w, 5 ln_k_b,
    // 6 Wq, 7 bq, 8 Wk, 9 bk, 10 Wv, 11 bv, 12 Wo, 13 bo
    const float* msa    = (const float*)d_in[0];
    const float* ln_k_b = (const float*)d_in[5];
    const float* Wv     = (const float*)d_in[10];
    const float* bv     = (const float*)d_in[11];
    const float* Wo     = (const float*)d_in[12];
    const float* bo     = (const float*)d_in[13];
    float* out     = (float*)d_out;
    float* partial = (float*)d_ws;   // ASPLIT * D floats of scratch

    saxs_msa_partial_c<<<ASPLIT, D, 0, stream>>>(ln_k_b, Wv, bv, Wo, bo, partial);

    const int n4 = out_size / 4;     // 1,048,576 float4s
    const int block = D;
    const int grid = 1024;           // 4 float4/thread, 16 waves/CU
    saxs_msa_add_c<<<grid, block, 0, stream>>>(msa, partial, out, n4);
}

// Round 3
// 12.800 us; speedup vs baseline: 1.6258x; 1.1619x over previous
//
#include <hip/hip_runtime.h>
#include <hip/hip_bf16.h>

// SAXSMSAAttention collapses algebraically:
//   kv_x = layer_norm(saxs[...,None]) over a size-1 axis == ln_k_b (exact: x-mu==0)
//   => k[l,:], v[l,:] constant over l => softmax exactly uniform (1/512)
//   => o[b,q,:] = v_const (whole Q path cancels)
//   => out = msa + c,  c = (ln_k_b*Wv + bv) @ Wo + bo   (a 256-vector)
// Valid for any finite inputs; c computed on-device from the actual buffers.
//
// Fused single-kernel version: each block redundantly computes c (identical
// bits in every block -> deterministic), overlapped with the preloaded
// msa streaming reads. One dispatch total.

#define D 256            // C_HID * N_HEADS == C_Q == 256
#define D4 (D / 4)       // 64 float4 columns
#define BLK 1024         // threads per block (16 waves)
#define NITER 4          // float4s per thread: 256 blk * 1024 thr * 4 = n4

__global__ __launch_bounds__(BLK) void saxs_msa_fused(
        const float* __restrict__ msa,
        const float* __restrict__ ln_k_b,
        const float* __restrict__ Wv,
        const float* __restrict__ bv,
        const float* __restrict__ Wo,
        const float* __restrict__ bo,
        float* __restrict__ out,
        int n4) {
    const int t = threadIdx.x;
    const int gsize = gridDim.x * BLK;
    const int base = blockIdx.x * BLK + t;

    // ---- 1) issue the streaming loads FIRST: HBM latency+BW overlaps prologue
    const float4* __restrict__ m4 = reinterpret_cast<const float4*>(msa);
    float4 m[NITER];
    const bool full = (base + (NITER - 1) * gsize) < n4;
    if (full) {
#pragma unroll
        for (int k = 0; k < NITER; ++k) m[k] = m4[base + k * gsize];
    } else {
#pragma unroll
        for (int k = 0; k < NITER; ++k)
            if (base + k * gsize < n4) m[k] = m4[base + k * gsize];
    }

    // ---- 2) prologue: c = (kb*Wv + bv) @ Wo + bo, float4 over columns
    __shared__ float vsh[D];
    __shared__ float4 psum4[16 * D4];   // 16 row-groups x 64 f4-cols = 16 KB
    __shared__ float4 csf4[D4];

    if (t < D) {
        const float kb = ln_k_b[0];
        vsh[t] = kb * Wv[t] + bv[t];
    }
    __syncthreads();

    {
        const int j4 = t & (D4 - 1);     // float4 column 0..63
        const int rg = t >> 6;           // row group 0..15 (16 rows each)
        const float4* __restrict__ Wo4 = reinterpret_cast<const float4*>(Wo);
        float4 facc = make_float4(0.f, 0.f, 0.f, 0.f);
#pragma unroll
        for (int i = rg * 16; i < rg * 16 + 16; ++i) {
            const float4 w = Wo4[i * D4 + j4];
            const float vi = vsh[i];
            facc.x += vi * w.x; facc.y += vi * w.y;
            facc.z += vi * w.z; facc.w += vi * w.w;
        }
        psum4[rg * D4 + j4] = facc;
    }
    __syncthreads();

    if (t < D4) {
        float4 cf = reinterpret_cast<const float4*>(bo)[t];
#pragma unroll
        for (int rg = 0; rg < 16; ++rg) {
            const float4 p = psum4[rg * D4 + t];
            cf.x += p.x; cf.y += p.y; cf.z += p.z; cf.w += p.w;
        }
        csf4[t] = cf;
    }
    __syncthreads();

    // ---- 3) add & store (column of f4 index i is i & 63; gsize % 64 == 0)
    const float4 cc = csf4[t & (D4 - 1)];
    float4* __restrict__ o4 = reinterpret_cast<float4*>(out);
    if (full) {
#pragma unroll
        for (int k = 0; k < NITER; ++k) {
            float4 r = m[k];
            r.x += cc.x; r.y += cc.y; r.z += cc.z; r.w += cc.w;
            o4[base + k * gsize] = r;
        }
    } else {
#pragma unroll
        for (int k = 0; k < NITER; ++k) {
            if (base + k * gsize < n4) {
                float4 r = m[k];
                r.x += cc.x; r.y += cc.y; r.z += cc.z; r.w += cc.w;
                o4[base + k * gsize] = r;
            }
        }
    }
}

extern "C" void kernel_launch(void* const* d_in, const int* in_sizes, int n_in,
                              void* d_out, int out_size, void* d_ws, size_t ws_size,
                              hipStream_t stream) {
    // setup_inputs order:
    // 0 msa, 1 saxs, 2 ln_q_w, 3 ln_q_b, 4 ln_k_w, 5 ln_k_b,
    // 6 Wq, 7 bq, 8 Wk, 9 bk, 10 Wv, 11 bv, 12 Wo, 13 bo
    const float* msa    = (const float*)d_in[0];
    const float* ln_k_b = (const float*)d_in[5];
    const float* Wv     = (const float*)d_in[10];
    const float* bv     = (const float*)d_in[11];
    const float* Wo     = (const float*)d_in[12];
    const float* bo     = (const float*)d_in[13];
    float* out = (float*)d_out;

    const int n4 = out_size / 4;                       // 1,048,576 float4s
    int grid = (n4 + BLK * NITER - 1) / (BLK * NITER); // = 256 exactly
    saxs_msa_fused<<<grid, BLK, 0, stream>>>(msa, ln_k_b, Wv, bv, Wo, bo, out, n4);
}